// Round 7
// baseline (192.778 us; speedup 1.0000x reference)
//
#include <hip/hip_runtime.h>

// OptimizedLinear: out = x@W^T + bias - lr[:,None]*(x@G^T + bias_grad)
// B=4096, IN=OUT=2048, fp32 in/out. bf16 MFMA fused dual-accumulator GEMM.
//
// Round 14: PIVOT — stop rescheduling, reduce LDS traffic. R7-R13 (six
// schedule variants: 1/2/4-phase x drain/counted/never-drain x mono/ring)
// all land 72-81us, MfmaUtil 33-40%: per-tile time == MFMA(2483cy) +
// LDS-reads(2300cy) + stage(500cy) SERIAL, and no barrier discipline
// overlaps them. So: A-fragments now load DIRECT from global to registers
// (each frag = 16 rows x contiguous 64B = sector-coalesced gather; x panel
// is L3-resident, by-panel L2-reused by 16 blocks). Removes 1/3 of LDS
// reads, halves staged bytes, and A-loads are compiler-pipelined with
// counted vmcnt (no barrier coupling). W/G stay staged via gload_lds with
// the R7-proven conflict-free granule-XOR layout (4-way wave reuse).
// LDS/block drops to 64KB -> back to 128x128/4-wave/2-blocks-per-CU (R7
// geometry): two independent blocks per CU overlap each other's sync
// drain with compute (m114). ONE __syncthreads per K-tile (stage issued
// before compute -> drain has a full tile of cover).
// Per-acc k-update order unchanged from R7-R13 -> absmax exactly 0.03125.
//
// Lessons carried: schedule family null at this geometry (R7-R13);
// granule-XOR layout conflict-free (R2-R13); frag ping-pong at 8 waves
// spills (R10, tripwire WRITE_SIZE >> 45MB); sched fences beyond rule-18
// poison (R9/R10); occupancy-by-launch-bounds not the lever (R4).
// Falsification for this round: gemm >= 70us & MfmaUtil ~38 -> LDS volume
// also not the term; R15 = MFMA-only ablation to measure the true floor.

typedef unsigned short ushort_t;
typedef __attribute__((ext_vector_type(8))) short short8;       // 8 bf16 = 4 VGPR
typedef __attribute__((ext_vector_type(8))) unsigned short ushort8;
typedef __attribute__((ext_vector_type(4))) float f32x4;

#define GPTR(p) ((const __attribute__((address_space(1))) void*)(p))
#define LPTR(p) ((__attribute__((address_space(3))) void*)(p))

static constexpr int Kdim = 2048;
static constexpr int Ndim = 2048;
static constexpr int BK   = 64;
static constexpr int BM   = 128;
static constexpr int BN   = 128;
static constexpr int NT   = Kdim / BK;   // 32 K-tiles

__device__ __forceinline__ unsigned short f2bf(float f) {
    union { float f; unsigned u; } c; c.f = f;
    unsigned u = c.u;
    unsigned r = (u + 0x7fffu + ((u >> 16) & 1u)) >> 16;  // RNE
    return (unsigned short)r;
}

// One launch converts x (uX ushort8-units), W (uW), G (uW). Unit = 8 elems.
__global__ void cvt_all_kernel(const float* __restrict__ x,
                               const float* __restrict__ W,
                               const float* __restrict__ G,
                               ushort_t* __restrict__ xb,
                               ushort_t* __restrict__ wb,
                               ushort_t* __restrict__ gb,
                               int uX, int uW) {
    int u = blockIdx.x * blockDim.x + threadIdx.x;
    const float* src; ushort_t* dst;
    if (u < uX)            { src = x; dst = xb; }
    else if (u < uX + uW)  { src = W; dst = wb; u -= uX; }
    else                   { src = G; dst = gb; u -= uX + uW; }
    int i = u * 8;
    float4 a = *(const float4*)(src + i);
    float4 b = *(const float4*)(src + i + 4);
    ushort8 r;
    r[0] = f2bf(a.x); r[1] = f2bf(a.y); r[2] = f2bf(a.z); r[3] = f2bf(a.w);
    r[4] = f2bf(b.x); r[5] = f2bf(b.y); r[6] = f2bf(b.z); r[7] = f2bf(b.w);
    *(ushort8*)(dst + i) = r;
}

// ---- fused dual GEMM, 128x128 tile, BK=64, 4 waves, A-direct ----
// 256 threads = 4 waves (2x2), each wave 64x64 = 4x4 MFMA tiles, dual acc.
// A: direct global->reg (8 x b128 gather per wave per tile, no LDS).
// W/G: LDS tiles 128x64 bf16, double-buffered: 64 KB -> 2 blocks/CU.
// Granule (row r, g=k/8) lives at slot r*8 + (g ^ (r&7)); swizzle applied
// on the GLOBAL fetch address (LDS dst is HW-forced to base + lane*16).
// Fragment read: addr = row*64 + ((j*4+quad) ^ (row&7))*8 -> conflict-free
// (0 bank conflicts measured across R2-R11 with this exact layout).
__global__ __launch_bounds__(256, 2) void fused_gemm_kernel(
    const ushort_t* __restrict__ xb,   // [4096, 2048] bf16
    const ushort_t* __restrict__ wb,   // [2048, 2048] bf16
    const ushort_t* __restrict__ gb,   // [2048, 2048] bf16
    const float* __restrict__ bias,    // [2048]
    const float* __restrict__ bgrad,   // [2048]
    const float* __restrict__ lr,      // [4096]
    float* __restrict__ out)           // [4096, 2048] fp32
{
    __shared__ ushort_t Ws[2][BN * BK];  // 2 x 16 KB
    __shared__ ushort_t Gs[2][BN * BK];  // 2 x 16 KB

    const int t    = threadIdx.x;
    const int wave = t >> 6;
    const int lane = t & 63;
    const int wm   = (wave >> 1) * 64;   // 0,64
    const int wn   = (wave & 1) * 64;    // 0,64

    // XCD-chunked bijective swizzle: 512 blocks, 8 XCDs, 64 blocks/XCD
    // = 4 by-rows x 16 bx per XCD.
    const int bid = blockIdx.y * 16 + blockIdx.x;
    const int swz = (bid & 7) * 64 + (bid >> 3);
    const int by  = swz >> 4;   // M tile (0..31)
    const int bx  = swz & 15;   // N tile (0..15)

    const int fr   = lane & 15;    // fragment row
    const int quad = lane >> 4;    // k-granule select (0..3)

    f32x4 accB[4][4] = {};
    f32x4 accP[4][4] = {};

    // --- A-direct addressing: per-lane row base, contiguous 64B per row ---
    // af[j][mt] = x[by*128 + wm + mt*16 + fr][k0 + j*32 + quad*8 .. +8]
    const ushort_t* pA[4];
#pragma unroll
    for (int mt = 0; mt < 4; ++mt)
        pA[mt] = xb + (size_t)(by * BM + wm + mt * 16 + fr) * Kdim + quad * 8;

    // --- W/G staging addressing (R7-proven): 1024 slots of 16B, 4 issues ---
    // slot s: row = s>>3, fetched granule q' = (s&7) ^ (row&7)
    const ushort_t* gW[4]; const ushort_t* gG[4]; int dW[4];
#pragma unroll
    for (int i = 0; i < 4; ++i) {
        int s   = i * 256 + t;
        int row = s >> 3;
        int q   = ((s & 7) ^ (row & 7)) * 8;
        gW[i] = wb + (size_t)(bx * BN + row) * Kdim + q;
        gG[i] = gb + (size_t)(bx * BN + row) * Kdim + q;
        dW[i] = (i * 256 + wave * 64) * 8;   // wave-uniform; HW adds lane*16B
    }

    short8 af[2][4], wf[4], gf[4];

#define GLDS(g, l) __builtin_amdgcn_global_load_lds(GPTR(g), LPTR(l), 16, 0, 0)

    // 8 gload_lds per thread per K-tile (4 W + 4 G)
#define STAGE(B, K0) do {                                                         \
    _Pragma("unroll")                                                             \
    for (int i = 0; i < 4; ++i) {                                                 \
        GLDS(gW[i] + (K0), &Ws[B][dW[i]]);                                        \
        GLDS(gG[i] + (K0), &Gs[B][dW[i]]);                                        \
    }                                                                             \
} while (0)

    // One K-tile: 8 A-gathers (both j), then per j {8 ds_reads; 32 MFMA}.
    // No fences: compiler pipelines A-loads/ds_reads into the MFMA stream
    // with counted vmcnt/lgkmcnt. Per-acc k-order identical to R7-R13.
#define COMPUTE(B, K0) do {                                                       \
    _Pragma("unroll")                                                             \
    for (int j = 0; j < 2; ++j)                                                   \
        _Pragma("unroll")                                                         \
        for (int mt = 0; mt < 4; ++mt)                                            \
            af[j][mt] = *(const short8*)(pA[mt] + (K0) + j * 32);                 \
    _Pragma("unroll")                                                             \
    for (int j = 0; j < 2; ++j) {                                                 \
        const int kc = ((j * 4 + quad) ^ (fr & 7)) * 8;                           \
        _Pragma("unroll")                                                         \
        for (int nt = 0; nt < 4; ++nt) {                                          \
            wf[nt] = *(const short8*)(&Ws[B][(wn + nt * 16 + fr) * BK + kc]);     \
            gf[nt] = *(const short8*)(&Gs[B][(wn + nt * 16 + fr) * BK + kc]);     \
        }                                                                         \
        __builtin_amdgcn_s_setprio(1);                                            \
        _Pragma("unroll")                                                         \
        for (int mt = 0; mt < 4; ++mt)                                            \
            _Pragma("unroll")                                                     \
            for (int nt = 0; nt < 4; ++nt) {                                      \
                accB[mt][nt] = __builtin_amdgcn_mfma_f32_16x16x32_bf16(           \
                    af[j][mt], wf[nt], accB[mt][nt], 0, 0, 0);                    \
                accP[mt][nt] = __builtin_amdgcn_mfma_f32_16x16x32_bf16(           \
                    af[j][mt], gf[nt], accP[mt][nt], 0, 0, 0);                    \
            }                                                                     \
        __builtin_amdgcn_s_setprio(0);                                            \
    }                                                                             \
} while (0)

    // prologue: stage tile 0 into buf0, publish
    STAGE(0, 0);
    __syncthreads();

    // steady state: ONE sync per tile. STAGE(t+1) issued first -> its
    // drain (inside the next __syncthreads) has a full COMPUTE of cover.
    // WAR: buf^1 was last read in tile t-1's COMPUTE, sealed by the sync
    // at the end of t-1. Two independent blocks/CU overlap sync drains.
    int buf = 0;
#pragma unroll 1
    for (int tt = 0; tt < NT - 1; ++tt) {
        STAGE(buf ^ 1, (tt + 1) * BK);
        COMPUTE(buf, tt * BK);
        __syncthreads();
        buf ^= 1;
    }
    COMPUTE(buf, (NT - 1) * BK);   // tile 31: no staging

#undef GLDS
#undef STAGE
#undef COMPUTE

    // --- epilogue: out = base + bias[n] - lr[m]*(pert + bgrad[n]) ---
    // C/D layout: col = lane&15, row = quad*4 + reg  (verified R2-R13)
    const int col = fr;
    const int gmb = by * BM + wm;
    const int gnb = bx * BN + wn;

    float lrv[4][4];
#pragma unroll
    for (int mt = 0; mt < 4; ++mt)
#pragma unroll
        for (int i = 0; i < 4; ++i)
            lrv[mt][i] = lr[gmb + mt * 16 + quad * 4 + i];

#pragma unroll
    for (int nt = 0; nt < 4; ++nt) {
        const int gn = gnb + nt * 16 + col;
        const float bn = bias[gn];
        const float bg = bgrad[gn];
#pragma unroll
        for (int mt = 0; mt < 4; ++mt) {
#pragma unroll
            for (int i = 0; i < 4; ++i) {
                const int gm = gmb + mt * 16 + quad * 4 + i;
                float v = accB[mt][nt][i] + bn - lrv[mt][i] * (accP[mt][nt][i] + bg);
                __builtin_nontemporal_store(v, out + (size_t)gm * Ndim + gn);
            }
        }
    }
}

extern "C" void kernel_launch(void* const* d_in, const int* in_sizes, int n_in,
                              void* d_out, int out_size, void* d_ws, size_t ws_size,
                              hipStream_t stream) {
    const float* x     = (const float*)d_in[0];  // [4096, 2048]
    const float* W     = (const float*)d_in[1];  // [2048, 2048]
    const float* bias  = (const float*)d_in[2];  // [2048]
    const float* G     = (const float*)d_in[3];  // [2048, 2048]
    const float* bgrad = (const float*)d_in[4];  // [2048]
    const float* lr    = (const float*)d_in[5];  // [4096]
    float* out = (float*)d_out;

    const int nX = 4096 * 2048;
    const int nW = 2048 * 2048;

    ushort_t* xb = (ushort_t*)d_ws;
    ushort_t* wb = xb + nX;
    ushort_t* gb = wb + nW;

    const int uX = nX / 8, uW = nW / 8;
    const int totalU = uX + 2 * uW;               // 2,097,152
    cvt_all_kernel<<<totalU / 256, 256, 0, stream>>>(x, W, G, xb, wb, gb, uX, uW);

    dim3 grid(16, 32);   // N tiles x M tiles = 512 blocks = 2/CU
    fused_gemm_kernel<<<grid, 256, 0, stream>>>(xb, wb, gb, bias, bgrad, lr, out);
}

// Round 8
// 172.299 us; speedup vs baseline: 1.1189x; 1.1189x over previous
//
#include <hip/hip_runtime.h>

// OptimizedLinear: out = x@W^T + bias - lr[:,None]*(x@G^T + bias_grad)
// B=4096, IN=OUT=2048, fp32 in/out. bf16 MFMA fused dual-accumulator GEMM.
//
// Round 15: switch MFMA shape 16x16x32 -> 32x32x16 on the R8 skeleton.
// Eight schedule variants (R7-R14) pin at 72-101us: wall time == LDS-pipe
// (98k cy/CU) + MFMA-pipe (79.5k cy/CU) serial, and scheduling can't
// overlap them (m232 records the same transplant failure). LDS bytes are
// tile-invariant at feasible reg budgets. The one additive lever left:
// the 32x32 pipe is ~17% faster per FLOP (2382 vs 2075 TF ubench; 8.07 vs
// 9.7 cy/32kFLOP) and halves MFMA instruction count. LDS traffic, staging,
// granule-XOR layout (conflict-free family, rederived: 8 lanes per 4-bank
// group, distinct rows - same as R2-R13's zero-conflict pattern), R8
// 2-barrier loop, grid, cvt: all verbatim.
// A/B frag (32x32x16 bf16): lane holds row/col = lane&31, k = (lane>>5)*8
// ..+8 (16B contiguous -> b128). C/D: col=lane&31, row=(reg&3)+8*(reg>>2)
// +4*(lane>>5) [HW-verified m74/m101]. acc = f32x16[2][2] x2 = 128 regs.
//
// Lessons carried: A must transpose through LDS - direct global gather
// explodes L2 requests (R14, -24us); schedule family null (R7-R13);
// granule-XOR conflict-free (R2-R13); 256-reg acc spills (R5/R10,
// tripwire WRITE_SIZE >> 45MB); fences beyond rule-18 poison (R9/R10);
// occupancy not the lever (R4).
// Falsification: gemm >= 71us -> MFMA-pipe term not additive-visible;
// R16 = producer/consumer wave specialization.

typedef unsigned short ushort_t;
typedef __attribute__((ext_vector_type(8))) short short8;        // 8 bf16 = 4 VGPR
typedef __attribute__((ext_vector_type(8))) unsigned short ushort8;
typedef __attribute__((ext_vector_type(16))) float f32x16;

#define GPTR(p) ((const __attribute__((address_space(1))) void*)(p))
#define LPTR(p) ((__attribute__((address_space(3))) void*)(p))

static constexpr int Kdim = 2048;
static constexpr int Ndim = 2048;
static constexpr int BK   = 64;
static constexpr int BM   = 256;
static constexpr int BN   = 128;
static constexpr int NT   = Kdim / BK;   // 32 K-tiles

__device__ __forceinline__ unsigned short f2bf(float f) {
    union { float f; unsigned u; } c; c.f = f;
    unsigned u = c.u;
    unsigned r = (u + 0x7fffu + ((u >> 16) & 1u)) >> 16;  // RNE
    return (unsigned short)r;
}

// One launch converts x (uX ushort8-units), W (uW), G (uW). Unit = 8 elems.
__global__ void cvt_all_kernel(const float* __restrict__ x,
                               const float* __restrict__ W,
                               const float* __restrict__ G,
                               ushort_t* __restrict__ xb,
                               ushort_t* __restrict__ wb,
                               ushort_t* __restrict__ gb,
                               int uX, int uW) {
    int u = blockIdx.x * blockDim.x + threadIdx.x;
    const float* src; ushort_t* dst;
    if (u < uX)            { src = x; dst = xb; }
    else if (u < uX + uW)  { src = W; dst = wb; u -= uX; }
    else                   { src = G; dst = gb; u -= uX + uW; }
    int i = u * 8;
    float4 a = *(const float4*)(src + i);
    float4 b = *(const float4*)(src + i + 4);
    ushort8 r;
    r[0] = f2bf(a.x); r[1] = f2bf(a.y); r[2] = f2bf(a.z); r[3] = f2bf(a.w);
    r[4] = f2bf(b.x); r[5] = f2bf(b.y); r[6] = f2bf(b.z); r[7] = f2bf(b.w);
    *(ushort8*)(dst + i) = r;
}

// ---- fused dual GEMM, 256x128 tile, BK=64, 8 waves, 32x32x16 MFMA ----
// 512 threads = 8 waves (4 M x 2 N), each wave 64x64 = 2x2 of 32x32 frags,
// dual acc (f32x16[2][2] x 2 = 128 regs). LDS: A 256x64, W/G 128x64 bf16,
// double-buffered: 128 KB (1 block/CU). Granule (row r, g=k/8) lives at
// slot r*8 + (g ^ (r&7)); swizzle applied on the GLOBAL fetch address
// (LDS dst is HW-forced to base + lane*16). Fragment read (mt/nt, ks):
// row = base + (lane&31), gs = ks*2 + (lane>>5), elem = row*64 +
// ((gs^(row&7))*8) -> 8 lanes per 4-bank granule group, distinct rows =
// the exact pattern family that measured 0 conflicts across R2-R13.
__global__ __launch_bounds__(512, 2) void fused_gemm_kernel(
    const ushort_t* __restrict__ xb,   // [4096, 2048] bf16
    const ushort_t* __restrict__ wb,   // [2048, 2048] bf16
    const ushort_t* __restrict__ gb,   // [2048, 2048] bf16
    const float* __restrict__ bias,    // [2048]
    const float* __restrict__ bgrad,   // [2048]
    const float* __restrict__ lr,      // [4096]
    float* __restrict__ out)           // [4096, 2048] fp32
{
    __shared__ ushort_t As[2][BM * BK];  // 2 x 32 KB
    __shared__ ushort_t Ws[2][BN * BK];  // 2 x 16 KB
    __shared__ ushort_t Gs[2][BN * BK];  // 2 x 16 KB

    const int t    = threadIdx.x;
    const int wave = t >> 6;
    const int lane = t & 63;
    const int wm   = (wave >> 1) * 64;   // 0,64,128,192
    const int wn   = (wave & 1) * 64;    // 0,64

    // XCD-chunked swizzle: 256 blocks, 8 XCDs, 32 blocks/XCD = 2 by-rows x 16 bx.
    const int bid = blockIdx.y * 16 + blockIdx.x;
    const int swz = (bid & 7) * 32 + (bid >> 3);
    const int by  = swz >> 4;   // M tile (0..15)
    const int bx  = swz & 15;   // N tile (0..15)

    const int l31 = lane & 31;     // fragment row/col within 32
    const int h   = lane >> 5;     // k-half select (0..1)
    const int l7  = lane & 7;      // row&7 for the granule XOR

    f32x16 accB[2][2] = {};
    f32x16 accP[2][2] = {};

    // --- staging addressing (verbatim R8) ---
    // A: 2048 slots of 16B (4 issues/thread). W/G: 1024 slots (2 issues each).
    // slot s: row = s>>3, fetched granule q' = (s&7) ^ (row&7)
    const ushort_t* gA[4]; int dA[4];
#pragma unroll
    for (int i = 0; i < 4; ++i) {
        int s   = i * 512 + t;
        int row = s >> 3;
        int q   = ((s & 7) ^ (row & 7)) * 8;
        gA[i] = xb + (size_t)(by * BM + row) * Kdim + q;
        dA[i] = (i * 512 + wave * 64) * 8;   // wave-uniform base; HW adds lane*16B
    }
    const ushort_t* gW[2]; const ushort_t* gG[2]; int dW[2];
#pragma unroll
    for (int i = 0; i < 2; ++i) {
        int s   = i * 512 + t;
        int row = s >> 3;
        int q   = ((s & 7) ^ (row & 7)) * 8;
        gW[i] = wb + (size_t)(bx * BN + row) * Kdim + q;
        gG[i] = gb + (size_t)(bx * BN + row) * Kdim + q;
        dW[i] = (i * 512 + wave * 64) * 8;
    }

    // per-thread read row bases
    const int rA = (wm + l31) * BK;      // + mt*32*BK
    const int rW = (wn + l31) * BK;      // + nt*32*BK

    // 8 global_load_lds per thread per K-tile (4 A + 2 W + 2 G)
#define STAGE(B, K0) do {                                                         \
    _Pragma("unroll")                                                             \
    for (int i = 0; i < 4; ++i)                                                   \
        __builtin_amdgcn_global_load_lds(GPTR(gA[i] + (K0)),                      \
                                         LPTR(&As[B][dA[i]]), 16, 0, 0);          \
    _Pragma("unroll")                                                             \
    for (int i = 0; i < 2; ++i) {                                                 \
        __builtin_amdgcn_global_load_lds(GPTR(gW[i] + (K0)),                      \
                                         LPTR(&Ws[B][dW[i]]), 16, 0, 0);          \
        __builtin_amdgcn_global_load_lds(GPTR(gG[i] + (K0)),                      \
                                         LPTR(&Gs[B][dW[i]]), 16, 0, 0);          \
    }                                                                             \
} while (0)

    // One K-tile on buffer B: 4 k-steps (K=16 each). Per ks: 6 ds_read_b128
    // (2 A, 2 W, 2 G) + 8 independent MFMAs. No fences: compiler pipelines
    // reads ahead across ks with counted lgkmcnt (register headroom ~200).
#define COMPUTE(B) do {                                                           \
    _Pragma("unroll")                                                             \
    for (int ks = 0; ks < 4; ++ks) {                                              \
        const int pg = ((2 * ks + h) ^ l7) * 8;                                   \
        short8 af[2], wf[2], gf[2];                                               \
        _Pragma("unroll")                                                         \
        for (int mt = 0; mt < 2; ++mt)                                            \
            af[mt] = *(const short8*)(&As[B][rA + mt * (32 * BK) + pg]);          \
        _Pragma("unroll")                                                         \
        for (int nt = 0; nt < 2; ++nt) {                                          \
            wf[nt] = *(const short8*)(&Ws[B][rW + nt * (32 * BK) + pg]);          \
            gf[nt] = *(const short8*)(&Gs[B][rW + nt * (32 * BK) + pg]);          \
        }                                                                         \
        __builtin_amdgcn_s_setprio(1);                                            \
        _Pragma("unroll")                                                         \
        for (int mt = 0; mt < 2; ++mt)                                            \
            _Pragma("unroll")                                                     \
            for (int nt = 0; nt < 2; ++nt) {                                      \
                accB[mt][nt] = __builtin_amdgcn_mfma_f32_32x32x16_bf16(           \
                    af[mt], wf[nt], accB[mt][nt], 0, 0, 0);                       \
                accP[mt][nt] = __builtin_amdgcn_mfma_f32_32x32x16_bf16(           \
                    af[mt], gf[nt], accP[mt][nt], 0, 0, 0);                       \
            }                                                                     \
        __builtin_amdgcn_s_setprio(0);                                            \
    }                                                                             \
} while (0)

#define WAITV(N) do {                                                             \
    __builtin_amdgcn_sched_barrier(0);                                            \
    asm volatile("s_waitcnt vmcnt(" #N ")" ::: "memory");                         \
    __builtin_amdgcn_sched_barrier(0);                                            \
} while (0)

    // prologue: tiles 0 and 1 in flight; wait for tile 0 only (oldest 8)
    STAGE(0, 0);
    STAGE(1, BK);
    WAITV(8);
    __builtin_amdgcn_s_barrier();

    // steady state (R8 skeleton verbatim): 8 loads (next-next tile) stay in
    // flight across every barrier; vmcnt(8) = tile t+1's loads landed.
#pragma unroll 1
    for (int tt = 0; tt < NT - 2; tt += 2) {
        COMPUTE(0);
        __builtin_amdgcn_s_barrier();
        STAGE(0, (tt + 2) * BK);
        WAITV(8);
        __builtin_amdgcn_s_barrier();

        COMPUTE(1);
        __builtin_amdgcn_s_barrier();
        STAGE(1, (tt + 3) * BK);
        WAITV(8);
        __builtin_amdgcn_s_barrier();
    }

    // tail: tile 30 (buf0), drain tile 31's loads, tile 31 (buf1)
    COMPUTE(0);
    __builtin_amdgcn_s_barrier();
    WAITV(0);
    __builtin_amdgcn_s_barrier();
    COMPUTE(1);

#undef STAGE
#undef COMPUTE
#undef WAITV

    // --- epilogue: out = base + bias[n] - lr[m]*(pert + bgrad[n]) ---
    // 32x32 C/D layout: col = lane&31, row = (reg&3)+8*(reg>>2)+4*(lane>>5)
    // [HW-verified m74/m101 on gfx950]
    const int gmb = by * BM + wm;
    const int gnb = bx * BN + wn;

    float lrv[2][16];
#pragma unroll
    for (int mt = 0; mt < 2; ++mt)
#pragma unroll
        for (int reg = 0; reg < 16; ++reg) {
            const int row = (reg & 3) + 8 * (reg >> 2) + 4 * h;
            lrv[mt][reg] = lr[gmb + mt * 32 + row];
        }

#pragma unroll
    for (int nt = 0; nt < 2; ++nt) {
        const int gn = gnb + nt * 32 + l31;
        const float bn = bias[gn];
        const float bg = bgrad[gn];
#pragma unroll
        for (int mt = 0; mt < 2; ++mt) {
#pragma unroll
            for (int reg = 0; reg < 16; ++reg) {
                const int row = (reg & 3) + 8 * (reg >> 2) + 4 * h;
                const int gm = gmb + mt * 32 + row;
                float v = accB[mt][nt][reg] + bn
                        - lrv[mt][reg] * (accP[mt][nt][reg] + bg);
                __builtin_nontemporal_store(v, out + (size_t)gm * Ndim + gn);
            }
        }
    }
}

extern "C" void kernel_launch(void* const* d_in, const int* in_sizes, int n_in,
                              void* d_out, int out_size, void* d_ws, size_t ws_size,
                              hipStream_t stream) {
    const float* x     = (const float*)d_in[0];  // [4096, 2048]
    const float* W     = (const float*)d_in[1];  // [2048, 2048]
    const float* bias  = (const float*)d_in[2];  // [2048]
    const float* G     = (const float*)d_in[3];  // [2048, 2048]
    const float* bgrad = (const float*)d_in[4];  // [2048]
    const float* lr    = (const float*)d_in[5];  // [4096]
    float* out = (float*)d_out;

    const int nX = 4096 * 2048;
    const int nW = 2048 * 2048;

    ushort_t* xb = (ushort_t*)d_ws;
    ushort_t* wb = xb + nX;
    ushort_t* gb = wb + nW;

    const int uX = nX / 8, uW = nW / 8;
    const int totalU = uX + 2 * uW;               // 2,097,152
    cvt_all_kernel<<<totalU / 256, 256, 0, stream>>>(x, W, G, xb, wb, gb, uX, uW);

    dim3 grid(16, 16);   // N tiles x M tiles = 256 blocks = 1/CU
    fused_gemm_kernel<<<grid, 512, 0, stream>>>(xb, wb, gb, bias, bgrad, lr, out);
}